// Round 1
// baseline (175.010 us; speedup 1.0000x reference)
//
#include <hip/hip_runtime.h>
#include <hip/hip_bf16.h>

// PhraseClassifier R11.
//   R10 counters: proj_gemm 43us with NOTHING saturated (Mfma 13%, VALU 10%,
//   HBM 16%); span_eval ~40us reading 268MB against a 16.8MB Wq table (16x
//   reuse) in RANDOM span order -> working set 16.8MB > 4MiB per-XCD L2, so
//   every read is L3-served (~6-7 TB/s). Fix 1: counting-sort span INDICES by
//   bid (rows are s*32+bid -> one bid = 512KB slab); XCD-swizzle span_eval
//   blocks so each XCD touches 4 bids = 2MB, L2-resident (34.5 TB/s agg).
//   Hot kernel unchanged except s = sidx[..] + block remap.
//   Fix 2: proj_gemm stage used bit-math RNE bf16 (~3 VALU/elem); native
//   (__bf16) casts emit v_cvt_pk_bf16_f32 (2 elem/instr), ~4x less stage VALU.

typedef float f32x4 __attribute__((ext_vector_type(4)));
typedef float f32x2 __attribute__((ext_vector_type(2)));
typedef __bf16 bf16x8 __attribute__((ext_vector_type(8)));

__device__ __forceinline__ unsigned short f2bf(float f) {
  unsigned int u = __float_as_uint(f);
  u += 0x7fffu + ((u >> 16) & 1u);   // RNE
  return (unsigned short)(u >> 16);
}
__device__ __forceinline__ float bf2f(unsigned int lo16) {
  return __uint_as_float(lo16 << 16);
}

// ---- prep: W1 [1024][512] fp32 -> W1b blocked [c=32][n=512][kk=32] bf16 ----
__global__ void w1_blocked(const float* __restrict__ W1,
                           unsigned short* __restrict__ W1b) {
  int idx = blockIdx.x * 256 + threadIdx.x;   // 0..65535
  int kc = idx & 3;                           // 8-k chunk within tile
  int n  = (idx >> 2) & 511;
  int c  = idx >> 11;                         // 0..31
  int k0 = c * 32 + kc * 8;
  unsigned short tmp[8];
#pragma unroll
  for (int j = 0; j < 8; ++j)
    tmp[j] = f2bf(W1[(k0 + j) * 512 + n]);
  *(uint4*)(W1b + c * 16384 + n * 32 + kc * 8) = *(uint4*)tmp;
}

// ---- span sort by bid: exact counting sort into sidx -------------------
// hist: per-block LDS histogram -> one global atomicAdd per bucket.
__global__ void span_hist(const int* __restrict__ bids, int* __restrict__ ghist,
                          int nspans) {
  __shared__ int h[32];
  int t = threadIdx.x;
  if (t < 32) h[t] = 0;
  __syncthreads();
  int base = blockIdx.x * 1024;
#pragma unroll
  for (int i = 0; i < 4; ++i) {
    int idx = base + t + i * 256;
    if (idx < nspans) atomicAdd(&h[bids[idx]], 1);
  }
  __syncthreads();
  if (t < 32) atomicAdd(&ghist[t], h[t]);
}

// scatter: each block reserves per-bucket chunks (atomicAdd on gslot),
// computes exclusive prefix of ghist in-register, writes span ids.
__global__ void span_scatter(const int* __restrict__ bids,
                             const int* __restrict__ ghist,
                             int* __restrict__ gslot,
                             int* __restrict__ sidx, int nspans) {
  __shared__ int lh[32], lbase[32], lcur[32];
  int t = threadIdx.x;
  if (t < 32) lh[t] = 0;
  __syncthreads();
  int base = blockIdx.x * 512;
  int myb[2];
#pragma unroll
  for (int i = 0; i < 2; ++i) {
    int idx = base + t + i * 256;
    myb[i] = (idx < nspans) ? bids[idx] : -1;
    if (myb[i] >= 0) atomicAdd(&lh[myb[i]], 1);
  }
  __syncthreads();
  if (t < 32) {
    int pre = 0;
    for (int j = 0; j < t; ++j) pre += ghist[j];   // exclusive prefix
    lbase[t] = pre + atomicAdd(&gslot[t], lh[t]);  // reserve chunk
    lcur[t] = 0;
  }
  __syncthreads();
#pragma unroll
  for (int i = 0; i < 2; ++i) {
    int b = myb[i];
    if (b >= 0) {
      int pos = lbase[b] + atomicAdd(&lcur[b], 1);
      sidx[pos] = base + t + i * 256;
    }
  }
}

// ---------------- proj_gemm: 64M x 512N per block, one K-half ----------------
#define APITCH 520
__global__ __launch_bounds__(256, 2) void proj_gemm(
    const float* __restrict__ hidden,        // [16384][1024]
    const unsigned short* __restrict__ w1b,  // blocked [32][512][32] bf16
    unsigned char* __restrict__ Wq) {        // [16384][1024] fp8: [U[r] | V[r+32]]
  __shared__ __align__(16) unsigned short AH[64 * APITCH];  // 66560 B
  unsigned short* Eb = AH;                   // overlay [4][32][136]

  const int t = threadIdx.x;
  const int lane = t & 63;
  const int w = t >> 6;
  const int r0 = blockIdx.x << 6;
  const int hk = blockIdx.y << 9;            // 0 (U) or 512 (V)
  const int q = lane >> 4;                   // k-sub 0..3
  const int m = lane & 15;

  // ---- stage A: 64 rows x 512 cols fp32 -> bf16 LDS via native cvt_pk.
  {
    const int col = (t & 31) << 4;           // 0,16,...,496
    const int rsub = t >> 5;                 // 0..7
#pragma unroll
    for (int p = 0; p < 8; ++p) {
      int row = (p << 3) + rsub;             // 0..63
      const float4* gp = (const float4*)(hidden + ((r0 + row) << 10) + hk + col);
      float4 f0 = gp[0], f1 = gp[1], f2 = gp[2], f3 = gp[3];
      bf16x8 va, vb;
      va[0] = (__bf16)f0.x; va[1] = (__bf16)f0.y;
      va[2] = (__bf16)f0.z; va[3] = (__bf16)f0.w;
      va[4] = (__bf16)f1.x; va[5] = (__bf16)f1.y;
      va[6] = (__bf16)f1.z; va[7] = (__bf16)f1.w;
      vb[0] = (__bf16)f2.x; vb[1] = (__bf16)f2.y;
      vb[2] = (__bf16)f2.z; vb[3] = (__bf16)f2.w;
      vb[4] = (__bf16)f3.x; vb[5] = (__bf16)f3.y;
      vb[6] = (__bf16)f3.z; vb[7] = (__bf16)f3.w;
      unsigned short* dst = AH + row * APITCH + col;
      *(bf16x8*)dst = va;
      *(bf16x8*)(dst + 8) = vb;
    }
  }
  __syncthreads();

  int boffn[8];
#pragma unroll
  for (int nt = 0; nt < 8; ++nt)
    boffn[nt] = (((w << 7) + (nt << 4) + m) << 5) + (q << 3);
  const unsigned short* w1base = w1b + (blockIdx.y << 18);

  f32x4 acc[4][8];
#pragma unroll
  for (int i = 0; i < 4; ++i)
#pragma unroll
    for (int j = 0; j < 8; ++j) acc[i][j] = (f32x4){0.f, 0.f, 0.f, 0.f};

#pragma unroll
  for (int it = 0; it < 16; ++it) {
    const unsigned short* bt = w1base + (it << 14);   // tile it
    bf16x8 bfr[8];
#pragma unroll
    for (int nt = 0; nt < 8; ++nt)
      bfr[nt] = *(const bf16x8*)(bt + boffn[nt]);
    bf16x8 af[4];
#pragma unroll
    for (int mt = 0; mt < 4; ++mt)
      af[mt] = *(const bf16x8*)(AH + ((mt << 4) + m) * APITCH + (it << 5) + (q << 3));
#pragma unroll
    for (int mt = 0; mt < 4; ++mt)
#pragma unroll
      for (int nt = 0; nt < 8; ++nt)
        acc[mt][nt] = __builtin_amdgcn_mfma_f32_16x16x32_bf16(af[mt], bfr[nt],
                                                              acc[mt][nt], 0, 0, 0);
  }
  __syncthreads();   // all waves done reading AH -> Eb may overlay it

  // ---- epilogue: wave-local repack + coalesced fp8 stores ----
#pragma unroll
  for (int pass = 0; pass < 2; ++pass) {
#pragma unroll
    for (int mh = 0; mh < 2; ++mh) {
      int mt = (pass << 1) + mh;
#pragma unroll
      for (int r = 0; r < 4; ++r) {
        int rr = (mh << 4) + ((lane >> 4) << 2) + r;   // 0..31
#pragma unroll
        for (int nt = 0; nt < 8; ++nt)
          Eb[((w << 5) + rr) * 136 + (nt << 4) + (lane & 15)] = f2bf(acc[mt][nt][r]);
      }
    }
#pragma unroll
    for (int i = 0; i < 8; ++i) {
      int task = (i << 6) + lane;
      int rr = task >> 4;
      int ck = task & 15;
      uint4 v = *(const uint4*)&Eb[((w << 5) + rr) * 136 + (ck << 3)];
      float f0 = bf2f(v.x & 0xffff), f1 = bf2f(v.x >> 16);
      float f2 = bf2f(v.y & 0xffff), f3 = bf2f(v.y >> 16);
      float f4 = bf2f(v.z & 0xffff), f5 = bf2f(v.z >> 16);
      float f6 = bf2f(v.w & 0xffff), f7 = bf2f(v.w >> 16);
      uint2 o;
      o.x = __builtin_amdgcn_cvt_pk_fp8_f32(f0, f1, 0, false);
      o.x = __builtin_amdgcn_cvt_pk_fp8_f32(f2, f3, o.x, true);
      o.y = __builtin_amdgcn_cvt_pk_fp8_f32(f4, f5, 0, false);
      o.y = __builtin_amdgcn_cvt_pk_fp8_f32(f6, f7, o.y, true);
      int grow = r0 + (pass << 5) + rr;
      int col = (w << 7) + (ck << 3);
      if (hk == 0) {
        *(uint2*)(Wq + (grow << 10) + col) = o;              // U[r]
      } else if (grow >= 32) {
        *(uint2*)(Wq + ((grow - 32) << 10) + 512 + col) = o; // V[r] -> row r-32
      }
    }
  }
}

// ---------------- span_eval: 1 span per half-wave, bid-sorted + XCD swizzle ----
#define SPB 64
__global__ __launch_bounds__(256) void span_eval(
    const unsigned char* __restrict__ Wq,
    const int* __restrict__ sidx,
    const int* __restrict__ bids, const int* __restrict__ begins,
    const int* __restrict__ ends, const int* __restrict__ flags,
    const float* __restrict__ weights,
    const float* __restrict__ b1, const float* __restrict__ w2,
    const float* __restrict__ b2, float* __restrict__ partials) {
  __shared__ int oB[SPB], oE[SPB], sfl[SPB];
  __shared__ float swt[SPB];
  __shared__ float red[4][3];
  const int t = threadIdx.x;
  const int lane = t & 63;
  const int w = t >> 6;
  const int h = lane >> 5;          // half-wave
  const int hl = lane & 31;

  // XCD swizzle: logical block lb so XCD x (~blockIdx%8) gets a contiguous
  // chunk of the bid-sorted span order -> 4 bids = 2MB slab, L2-resident.
  const int nblk = gridDim.x;
  int lb = blockIdx.x;
  if ((nblk & 7) == 0) {
    const int cpx = nblk >> 3;
    lb = (blockIdx.x & 7) * cpx + (blockIdx.x >> 3);
  }
  const int sbase = lb * SPB;

  if (t < SPB) {
    int s = sidx[sbase + t];
    int b = bids[s], bg = begins[s], en = ends[s];
    oB[t] = (((bg - 1) << 5) + b) << 10;   // row b-1: [U[b-1] | V[b]]
    oE[t] = (((en - 1) << 5) + b) << 10;   // row e-1: [U[e-1] | V[e]]
    sfl[t] = flags[s];
    swt[t] = weights[s];
  }
  __syncthreads();

  const int sp0 = ((w << 1) + h) << 3;   // my half-wave's first span (block-local)
  const int c0 = hl << 4;                // 16 u-cols per lane
  float b1v[16], w2v[16];
#pragma unroll
  for (int q = 0; q < 4; ++q) {
    float4 bv = *(const float4*)(b1 + c0 + (q << 2));
    float4 wv = *(const float4*)(w2 + c0 + (q << 2));
    b1v[(q << 2) + 0] = bv.x; b1v[(q << 2) + 1] = bv.y;
    b1v[(q << 2) + 2] = bv.z; b1v[(q << 2) + 3] = bv.w;
    w2v[(q << 2) + 0] = wv.x; w2v[(q << 2) + 1] = wv.y;
    w2v[(q << 2) + 2] = wv.z; w2v[(q << 2) + 3] = wv.w;
  }

  auto dec = [](unsigned int v, float* f) {
    f32x2 a = __builtin_amdgcn_cvt_pk_f32_fp8(v, false);
    f32x2 b = __builtin_amdgcn_cvt_pk_f32_fp8(v, true);
    f[0] = a[0]; f[1] = a[1]; f[2] = b[0]; f[3] = b[1];
  };

  uint4 BU[3], BV[3], EU[3], EV[3];
  auto ld = [&](int slot, int j) {
    int ob = oB[sp0 + j], oe = oE[sp0 + j];
    BU[slot] = *(const uint4*)(Wq + ob + c0);        // U[b-1] chunk
    BV[slot] = *(const uint4*)(Wq + ob + 512 + c0);  // V[b]   chunk
    EU[slot] = *(const uint4*)(Wq + oe + c0);        // U[e-1] chunk
    EV[slot] = *(const uint4*)(Wq + oe + 512 + c0);  // V[e]   chunk
  };
  ld(0, 0); ld(1, 1); ld(2, 2);

  float mylogit = 0.f;
#pragma unroll
  for (int j = 0; j < 8; ++j) {
    const int slot = j % 3;
    float buf[16], bvf[16], euf[16], evf[16];
    dec(BU[slot].x, buf); dec(BU[slot].y, buf + 4);
    dec(BU[slot].z, buf + 8); dec(BU[slot].w, buf + 12);
    dec(BV[slot].x, bvf); dec(BV[slot].y, bvf + 4);
    dec(BV[slot].z, bvf + 8); dec(BV[slot].w, bvf + 12);
    dec(EU[slot].x, euf); dec(EU[slot].y, euf + 4);
    dec(EU[slot].z, euf + 8); dec(EU[slot].w, euf + 12);
    dec(EV[slot].x, evf); dec(EV[slot].y, evf + 4);
    dec(EV[slot].z, evf + 8); dec(EV[slot].w, evf + 12);
    if (j + 3 < 8) ld(slot, j + 3);
    float sv = 0.f;
#pragma unroll
    for (int k = 0; k < 16; ++k) {
      float zp = euf[k] - buf[k] + bvf[k] - evf[k] + b1v[k];
      sv += fmaxf(zp, 0.f) * w2v[k];
    }
    sv += __shfl_xor(sv, 1);
    sv += __shfl_xor(sv, 2);
    sv += __shfl_xor(sv, 4);
    sv += __shfl_xor(sv, 8);
    sv += __shfl_xor(sv, 16);       // reduce within half-wave
    if (hl == j) mylogit = sv;      // lane h*32+j parks span sp0+j
  }

  // span w*16+l (l<16) parked at lane ((l&8)<<2)+(l&7)
  mylogit = __shfl(mylogit, ((lane & 8) << 2) + (lane & 7));

  float pos_t = 0.f, neg_t = 0.f, cnt_t = 0.f;
  if (lane < 16) {
    int sl = (w << 4) + lane;       // block-local span id
    float logit = mylogit + b2[0];
    float p = 1.f / (1.f + expf(-logit));
    p = fminf(fmaxf(p, 1e-7f), 1.f - 1e-7f);
    int fl = sfl[sl];
    float bce = (fl == 1) ? -logf(p) : -logf(1.f - p);
    float term = swt[sl] * bce;
    pos_t = (fl == 1) ? term : 0.f;
    neg_t = (fl == 1) ? 0.f : term;
    cnt_t = (fl == 1) ? 1.f : 0.f;
  }
#pragma unroll
  for (int off = 1; off < 64; off <<= 1) {
    pos_t += __shfl_xor(pos_t, off);
    neg_t += __shfl_xor(neg_t, off);
    cnt_t += __shfl_xor(cnt_t, off);
  }
  if (lane == 0) { red[w][0] = pos_t; red[w][1] = neg_t; red[w][2] = cnt_t; }
  __syncthreads();
  if (t == 0) {
    partials[(blockIdx.x << 2) + 0] = red[0][0] + red[1][0] + red[2][0] + red[3][0];
    partials[(blockIdx.x << 2) + 1] = red[0][1] + red[1][1] + red[2][1] + red[3][1];
    partials[(blockIdx.x << 2) + 2] = red[0][2] + red[1][2] + red[2][2] + red[3][2];
  }
}

// ---------------- finalize ----------------
__global__ void finalize(const float* __restrict__ parts, int nblk,
                         float* __restrict__ out, int nspans) {
  __shared__ float sp[4], sn[4], sc[4];
  float P = 0.f, Ng = 0.f, C = 0.f;
  for (int i = threadIdx.x; i < nblk; i += 256) {
    P += parts[(i << 2) + 0];
    Ng += parts[(i << 2) + 1];
    C += parts[(i << 2) + 2];
  }
#pragma unroll
  for (int off = 1; off < 64; off <<= 1) {
    P += __shfl_xor(P, off);
    Ng += __shfl_xor(Ng, off);
    C += __shfl_xor(C, off);
  }
  int w = threadIdx.x >> 6;
  if ((threadIdx.x & 63) == 0) { sp[w] = P; sn[w] = Ng; sc[w] = C; }
  __syncthreads();
  if (threadIdx.x == 0) {
    P = sp[0] + sp[1] + sp[2] + sp[3];
    Ng = sn[0] + sn[1] + sn[2] + sn[3];
    C = sc[0] + sc[1] + sc[2] + sc[3];
    float scale = 2.f * C / (float)nspans;
    out[0] = (P + scale * Ng) / (float)nspans;
  }
}

extern "C" void kernel_launch(void* const* d_in, const int* in_sizes, int n_in,
                              void* d_out, int out_size, void* d_ws, size_t ws_size,
                              hipStream_t stream) {
  const float* hidden = (const float*)d_in[0];
  const int* bids     = (const int*)d_in[1];
  const int* begins   = (const int*)d_in[2];
  const int* ends     = (const int*)d_in[3];
  const int* flags    = (const int*)d_in[4];
  const float* weights = (const float*)d_in[5];
  const float* W1 = (const float*)d_in[6];
  const float* b1 = (const float*)d_in[7];
  const float* W2 = (const float*)d_in[8];
  const float* b2 = (const float*)d_in[9];
  float* out = (float*)d_out;
  const int nspans = in_sizes[1];       // 131072
  const int nblk = nspans / SPB;        // 2048

  float* partials = (float*)d_ws;                                    // 32 KiB
  unsigned short* W1b = (unsigned short*)((char*)d_ws + (1 << 18));  // 1 MiB blocked
  unsigned char* Wq = (unsigned char*)((char*)d_ws + (2 << 20));     // 16.8 MiB
  int* ghist = (int*)((char*)d_ws + (19 << 20));                     // 32 ints
  int* gslot = ghist + 32;                                           // 32 ints
  int* sidx  = (int*)((char*)d_ws + (20 << 20));                     // 512 KiB

  hipMemsetAsync(ghist, 0, 64 * sizeof(int), stream);
  w1_blocked<<<256, 256, 0, stream>>>(W1, W1b);
  span_hist<<<(nspans + 1023) / 1024, 256, 0, stream>>>(bids, ghist, nspans);
  span_scatter<<<(nspans + 511) / 512, 256, 0, stream>>>(bids, ghist, gslot,
                                                         sidx, nspans);
  proj_gemm<<<dim3(256, 2), 256, 0, stream>>>(hidden, W1b, Wq);
  span_eval<<<nblk, 256, 0, stream>>>(Wq, sidx, bids, begins, ends, flags,
                                      weights, b1, W2, b2, partials);
  finalize<<<1, 256, 0, stream>>>(partials, nblk, out, nspans);
}

// Round 2
// 171.967 us; speedup vs baseline: 1.0177x; 1.0177x over previous
//
#include <hip/hip_runtime.h>
#include <hip/hip_bf16.h>

// PhraseClassifier R12.
//   R11 post-mortem: bid-sort+swizzle for span_eval was net ~0 (sort cost ~=
//   gain); kept (no harm, possible upside). The unambiguous signal: proj_gemm
//   43-47us with MfmaUtil 13%, VALU 9%, HBM 16%, Occupancy 17% -> latency-
//   bound. Cause: 66.5KB LDS caps 2 blocks/CU; 256-thread blocks -> only
//   2 waves/SIMD; acc[4][8]=128 VGPR left the compiler zero pipelining room.
//   Fix: same 64Mx512N tile, 512 threads / 8 waves (64-col band per wave),
//   acc[4][4]=64 VGPR, 2 blocks/CU -> 4 waves/SIMD. Same B traffic (L2-
//   resident 2MB W1b). APITCH 520->522 (dword stride 5 mod 32) kills the
//   8-way A-frag bank conflict (917K conflict cycles).

typedef float f32x4 __attribute__((ext_vector_type(4)));
typedef float f32x2 __attribute__((ext_vector_type(2)));
typedef __bf16 bf16x8 __attribute__((ext_vector_type(8)));

__device__ __forceinline__ unsigned short f2bf(float f) {
  unsigned int u = __float_as_uint(f);
  u += 0x7fffu + ((u >> 16) & 1u);   // RNE
  return (unsigned short)(u >> 16);
}
__device__ __forceinline__ float bf2f(unsigned int lo16) {
  return __uint_as_float(lo16 << 16);
}

// ---- prep: W1 [1024][512] fp32 -> W1b blocked [c=32][n=512][kk=32] bf16 ----
__global__ void w1_blocked(const float* __restrict__ W1,
                           unsigned short* __restrict__ W1b) {
  int idx = blockIdx.x * 256 + threadIdx.x;   // 0..65535
  int kc = idx & 3;                           // 8-k chunk within tile
  int n  = (idx >> 2) & 511;
  int c  = idx >> 11;                         // 0..31
  int k0 = c * 32 + kc * 8;
  unsigned short tmp[8];
#pragma unroll
  for (int j = 0; j < 8; ++j)
    tmp[j] = f2bf(W1[(k0 + j) * 512 + n]);
  *(uint4*)(W1b + c * 16384 + n * 32 + kc * 8) = *(uint4*)tmp;
}

// ---- span sort by bid: exact counting sort into sidx -------------------
__global__ void span_hist(const int* __restrict__ bids, int* __restrict__ ghist,
                          int nspans) {
  __shared__ int h[32];
  int t = threadIdx.x;
  if (t < 32) h[t] = 0;
  __syncthreads();
  int base = blockIdx.x * 1024;
#pragma unroll
  for (int i = 0; i < 4; ++i) {
    int idx = base + t + i * 256;
    if (idx < nspans) atomicAdd(&h[bids[idx]], 1);
  }
  __syncthreads();
  if (t < 32) atomicAdd(&ghist[t], h[t]);
}

__global__ void span_scatter(const int* __restrict__ bids,
                             const int* __restrict__ ghist,
                             int* __restrict__ gslot,
                             int* __restrict__ sidx, int nspans) {
  __shared__ int lh[32], lbase[32], lcur[32];
  int t = threadIdx.x;
  if (t < 32) lh[t] = 0;
  __syncthreads();
  int base = blockIdx.x * 512;
  int myb[2];
#pragma unroll
  for (int i = 0; i < 2; ++i) {
    int idx = base + t + i * 256;
    myb[i] = (idx < nspans) ? bids[idx] : -1;
    if (myb[i] >= 0) atomicAdd(&lh[myb[i]], 1);
  }
  __syncthreads();
  if (t < 32) {
    int pre = 0;
    for (int j = 0; j < t; ++j) pre += ghist[j];   // exclusive prefix
    lbase[t] = pre + atomicAdd(&gslot[t], lh[t]);  // reserve chunk
    lcur[t] = 0;
  }
  __syncthreads();
#pragma unroll
  for (int i = 0; i < 2; ++i) {
    int b = myb[i];
    if (b >= 0) {
      int pos = lbase[b] + atomicAdd(&lcur[b], 1);
      sidx[pos] = base + t + i * 256;
    }
  }
}

// ---------------- proj_gemm: 64M x 512N per block, one K-half ----------------
// 512 threads / 8 waves, wave w owns cols [w*64, w*64+64): acc 4m x 4n.
// A staged contiguous in LDS (APITCH 522 -> conflict-free frag reads),
// B frags DIRECT global->VGPR from blocked W1b (1KB contiguous per load).
#define APITCH 522
__global__ __launch_bounds__(512, 4) void proj_gemm(
    const float* __restrict__ hidden,        // [16384][1024]
    const unsigned short* __restrict__ w1b,  // blocked [32][512][32] bf16
    unsigned char* __restrict__ Wq) {        // [16384][1024] fp8: [U[r] | V[r+32]]
  __shared__ __align__(16) unsigned short AH[64 * APITCH];  // 66816 B
  unsigned short* Eb = AH;                   // overlay [8][32][72] = 36864 B

  const int t = threadIdx.x;                 // 0..511
  const int lane = t & 63;
  const int w = t >> 6;                      // 0..7
  const int r0 = blockIdx.x << 6;
  const int hk = blockIdx.y << 9;            // 0 (U) or 512 (V)
  const int q = lane >> 4;                   // k-sub 0..3
  const int m = lane & 15;

  // ---- stage A: 64 rows x 512 cols fp32 -> bf16 LDS (native cvt_pk) ----
  {
    const int col = (t & 31) << 4;           // 0,16,...,496
    const int rsub = t >> 5;                 // 0..15
#pragma unroll
    for (int p = 0; p < 4; ++p) {
      int row = (p << 4) + rsub;             // 0..63
      const float4* gp = (const float4*)(hidden + ((r0 + row) << 10) + hk + col);
      float4 f0 = gp[0], f1 = gp[1], f2 = gp[2], f3 = gp[3];
      bf16x8 va, vb;
      va[0] = (__bf16)f0.x; va[1] = (__bf16)f0.y;
      va[2] = (__bf16)f0.z; va[3] = (__bf16)f0.w;
      va[4] = (__bf16)f1.x; va[5] = (__bf16)f1.y;
      va[6] = (__bf16)f1.z; va[7] = (__bf16)f1.w;
      vb[0] = (__bf16)f2.x; vb[1] = (__bf16)f2.y;
      vb[2] = (__bf16)f2.z; vb[3] = (__bf16)f2.w;
      vb[4] = (__bf16)f3.x; vb[5] = (__bf16)f3.y;
      vb[6] = (__bf16)f3.z; vb[7] = (__bf16)f3.w;
      unsigned short* dst = AH + row * APITCH + col;
      *(bf16x8*)dst = va;
      *(bf16x8*)(dst + 8) = vb;
    }
  }
  __syncthreads();

  int boffn[4];
#pragma unroll
  for (int nt = 0; nt < 4; ++nt)
    boffn[nt] = (((w << 6) + (nt << 4) + m) << 5) + (q << 3);
  const unsigned short* w1base = w1b + (blockIdx.y << 18);

  f32x4 acc[4][4];
#pragma unroll
  for (int i = 0; i < 4; ++i)
#pragma unroll
    for (int j = 0; j < 4; ++j) acc[i][j] = (f32x4){0.f, 0.f, 0.f, 0.f};

#pragma unroll
  for (int it = 0; it < 16; ++it) {
    const unsigned short* bt = w1base + (it << 14);   // tile it
    bf16x8 bfr[4];
#pragma unroll
    for (int nt = 0; nt < 4; ++nt)
      bfr[nt] = *(const bf16x8*)(bt + boffn[nt]);
    bf16x8 af[4];
#pragma unroll
    for (int mt = 0; mt < 4; ++mt)
      af[mt] = *(const bf16x8*)(AH + ((mt << 4) + m) * APITCH + (it << 5) + (q << 3));
#pragma unroll
    for (int mt = 0; mt < 4; ++mt)
#pragma unroll
      for (int nt = 0; nt < 4; ++nt)
        acc[mt][nt] = __builtin_amdgcn_mfma_f32_16x16x32_bf16(af[mt], bfr[nt],
                                                              acc[mt][nt], 0, 0, 0);
  }
  __syncthreads();   // all waves done reading AH -> Eb may overlay it

  // ---- epilogue: wave-local repack (32 rows x 64 cols per pass) + fp8 stores
  // C/D layout: col = lane&15, row = (lane>>4)*4 + reg.
  unsigned short* Ew = Eb + w * (32 * 72);   // wave-local band, 16B-aligned
#pragma unroll
  for (int pass = 0; pass < 2; ++pass) {
#pragma unroll
    for (int mh = 0; mh < 2; ++mh) {
      int mt = (pass << 1) + mh;
#pragma unroll
      for (int r = 0; r < 4; ++r) {
        int rr = (mh << 4) + ((lane >> 4) << 2) + r;   // 0..31
#pragma unroll
        for (int nt = 0; nt < 4; ++nt)
          Ew[rr * 72 + (nt << 4) + m] = f2bf(acc[mt][nt][r]);
      }
    }
    // 32 rows x 64 cols = 256 8-byte tasks = 4 iters x 64 lanes
#pragma unroll
    for (int i = 0; i < 4; ++i) {
      int task = (i << 6) + lane;
      int rr = task >> 3;                    // 0..31
      int ck = task & 7;                     // 0..7
      uint4 v = *(const uint4*)&Ew[rr * 72 + (ck << 3)];
      float f0 = bf2f(v.x & 0xffff), f1 = bf2f(v.x >> 16);
      float f2 = bf2f(v.y & 0xffff), f3 = bf2f(v.y >> 16);
      float f4 = bf2f(v.z & 0xffff), f5 = bf2f(v.z >> 16);
      float f6 = bf2f(v.w & 0xffff), f7 = bf2f(v.w >> 16);
      uint2 o;
      o.x = __builtin_amdgcn_cvt_pk_fp8_f32(f0, f1, 0, false);
      o.x = __builtin_amdgcn_cvt_pk_fp8_f32(f2, f3, o.x, true);
      o.y = __builtin_amdgcn_cvt_pk_fp8_f32(f4, f5, 0, false);
      o.y = __builtin_amdgcn_cvt_pk_fp8_f32(f6, f7, o.y, true);
      int grow = r0 + (pass << 5) + rr;
      int col = (w << 6) + (ck << 3);
      if (hk == 0) {
        *(uint2*)(Wq + (grow << 10) + col) = o;              // U[r]
      } else if (grow >= 32) {
        *(uint2*)(Wq + ((grow - 32) << 10) + 512 + col) = o; // V[r] -> row r-32
      }
    }
    // Ew band is wave-local; compiler orders pass1 writes after pass0 reads
  }
}

// ---------------- span_eval: 1 span per half-wave, bid-sorted + XCD swizzle ----
#define SPB 64
__global__ __launch_bounds__(256) void span_eval(
    const unsigned char* __restrict__ Wq,
    const int* __restrict__ sidx,
    const int* __restrict__ bids, const int* __restrict__ begins,
    const int* __restrict__ ends, const int* __restrict__ flags,
    const float* __restrict__ weights,
    const float* __restrict__ b1, const float* __restrict__ w2,
    const float* __restrict__ b2, float* __restrict__ partials) {
  __shared__ int oB[SPB], oE[SPB], sfl[SPB];
  __shared__ float swt[SPB];
  __shared__ float red[4][3];
  const int t = threadIdx.x;
  const int lane = t & 63;
  const int w = t >> 6;
  const int h = lane >> 5;          // half-wave
  const int hl = lane & 31;

  // XCD swizzle: each XCD gets a contiguous chunk of the bid-sorted span
  // order -> 4 bids = 2MB slab, L2-resident.
  const int nblk = gridDim.x;
  int lb = blockIdx.x;
  if ((nblk & 7) == 0) {
    const int cpx = nblk >> 3;
    lb = (blockIdx.x & 7) * cpx + (blockIdx.x >> 3);
  }
  const int sbase = lb * SPB;

  if (t < SPB) {
    int s = sidx[sbase + t];
    int b = bids[s], bg = begins[s], en = ends[s];
    oB[t] = (((bg - 1) << 5) + b) << 10;   // row b-1: [U[b-1] | V[b]]
    oE[t] = (((en - 1) << 5) + b) << 10;   // row e-1: [U[e-1] | V[e]]
    sfl[t] = flags[s];
    swt[t] = weights[s];
  }
  __syncthreads();

  const int sp0 = ((w << 1) + h) << 3;   // my half-wave's first span (block-local)
  const int c0 = hl << 4;                // 16 u-cols per lane
  float b1v[16], w2v[16];
#pragma unroll
  for (int q = 0; q < 4; ++q) {
    float4 bv = *(const float4*)(b1 + c0 + (q << 2));
    float4 wv = *(const float4*)(w2 + c0 + (q << 2));
    b1v[(q << 2) + 0] = bv.x; b1v[(q << 2) + 1] = bv.y;
    b1v[(q << 2) + 2] = bv.z; b1v[(q << 2) + 3] = bv.w;
    w2v[(q << 2) + 0] = wv.x; w2v[(q << 2) + 1] = wv.y;
    w2v[(q << 2) + 2] = wv.z; w2v[(q << 2) + 3] = wv.w;
  }

  auto dec = [](unsigned int v, float* f) {
    f32x2 a = __builtin_amdgcn_cvt_pk_f32_fp8(v, false);
    f32x2 b = __builtin_amdgcn_cvt_pk_f32_fp8(v, true);
    f[0] = a[0]; f[1] = a[1]; f[2] = b[0]; f[3] = b[1];
  };

  uint4 BU[3], BV[3], EU[3], EV[3];
  auto ld = [&](int slot, int j) {
    int ob = oB[sp0 + j], oe = oE[sp0 + j];
    BU[slot] = *(const uint4*)(Wq + ob + c0);        // U[b-1] chunk
    BV[slot] = *(const uint4*)(Wq + ob + 512 + c0);  // V[b]   chunk
    EU[slot] = *(const uint4*)(Wq + oe + c0);        // U[e-1] chunk
    EV[slot] = *(const uint4*)(Wq + oe + 512 + c0);  // V[e]   chunk
  };
  ld(0, 0); ld(1, 1); ld(2, 2);

  float mylogit = 0.f;
#pragma unroll
  for (int j = 0; j < 8; ++j) {
    const int slot = j % 3;
    float buf[16], bvf[16], euf[16], evf[16];
    dec(BU[slot].x, buf); dec(BU[slot].y, buf + 4);
    dec(BU[slot].z, buf + 8); dec(BU[slot].w, buf + 12);
    dec(BV[slot].x, bvf); dec(BV[slot].y, bvf + 4);
    dec(BV[slot].z, bvf + 8); dec(BV[slot].w, bvf + 12);
    dec(EU[slot].x, euf); dec(EU[slot].y, euf + 4);
    dec(EU[slot].z, euf + 8); dec(EU[slot].w, euf + 12);
    dec(EV[slot].x, evf); dec(EV[slot].y, evf + 4);
    dec(EV[slot].z, evf + 8); dec(EV[slot].w, evf + 12);
    if (j + 3 < 8) ld(slot, j + 3);
    float sv = 0.f;
#pragma unroll
    for (int k = 0; k < 16; ++k) {
      float zp = euf[k] - buf[k] + bvf[k] - evf[k] + b1v[k];
      sv += fmaxf(zp, 0.f) * w2v[k];
    }
    sv += __shfl_xor(sv, 1);
    sv += __shfl_xor(sv, 2);
    sv += __shfl_xor(sv, 4);
    sv += __shfl_xor(sv, 8);
    sv += __shfl_xor(sv, 16);       // reduce within half-wave
    if (hl == j) mylogit = sv;      // lane h*32+j parks span sp0+j
  }

  // span w*16+l (l<16) parked at lane ((l&8)<<2)+(l&7)
  mylogit = __shfl(mylogit, ((lane & 8) << 2) + (lane & 7));

  float pos_t = 0.f, neg_t = 0.f, cnt_t = 0.f;
  if (lane < 16) {
    int sl = (w << 4) + lane;       // block-local span id
    float logit = mylogit + b2[0];
    float p = 1.f / (1.f + expf(-logit));
    p = fminf(fmaxf(p, 1e-7f), 1.f - 1e-7f);
    int fl = sfl[sl];
    float bce = (fl == 1) ? -logf(p) : -logf(1.f - p);
    float term = swt[sl] * bce;
    pos_t = (fl == 1) ? term : 0.f;
    neg_t = (fl == 1) ? 0.f : term;
    cnt_t = (fl == 1) ? 1.f : 0.f;
  }
#pragma unroll
  for (int off = 1; off < 64; off <<= 1) {
    pos_t += __shfl_xor(pos_t, off);
    neg_t += __shfl_xor(neg_t, off);
    cnt_t += __shfl_xor(cnt_t, off);
  }
  if (lane == 0) { red[w][0] = pos_t; red[w][1] = neg_t; red[w][2] = cnt_t; }
  __syncthreads();
  if (t == 0) {
    partials[(blockIdx.x << 2) + 0] = red[0][0] + red[1][0] + red[2][0] + red[3][0];
    partials[(blockIdx.x << 2) + 1] = red[0][1] + red[1][1] + red[2][1] + red[3][1];
    partials[(blockIdx.x << 2) + 2] = red[0][2] + red[1][2] + red[2][2] + red[3][2];
  }
}

// ---------------- finalize ----------------
__global__ void finalize(const float* __restrict__ parts, int nblk,
                         float* __restrict__ out, int nspans) {
  __shared__ float sp[4], sn[4], sc[4];
  float P = 0.f, Ng = 0.f, C = 0.f;
  for (int i = threadIdx.x; i < nblk; i += 256) {
    P += parts[(i << 2) + 0];
    Ng += parts[(i << 2) + 1];
    C += parts[(i << 2) + 2];
  }
#pragma unroll
  for (int off = 1; off < 64; off <<= 1) {
    P += __shfl_xor(P, off);
    Ng += __shfl_xor(Ng, off);
    C += __shfl_xor(C, off);
  }
  int w = threadIdx.x >> 6;
  if ((threadIdx.x & 63) == 0) { sp[w] = P; sn[w] = Ng; sc[w] = C; }
  __syncthreads();
  if (threadIdx.x == 0) {
    P = sp[0] + sp[1] + sp[2] + sp[3];
    Ng = sn[0] + sn[1] + sn[2] + sn[3];
    C = sc[0] + sc[1] + sc[2] + sc[3];
    float scale = 2.f * C / (float)nspans;
    out[0] = (P + scale * Ng) / (float)nspans;
  }
}

extern "C" void kernel_launch(void* const* d_in, const int* in_sizes, int n_in,
                              void* d_out, int out_size, void* d_ws, size_t ws_size,
                              hipStream_t stream) {
  const float* hidden = (const float*)d_in[0];
  const int* bids     = (const int*)d_in[1];
  const int* begins   = (const int*)d_in[2];
  const int* ends     = (const int*)d_in[3];
  const int* flags    = (const int*)d_in[4];
  const float* weights = (const float*)d_in[5];
  const float* W1 = (const float*)d_in[6];
  const float* b1 = (const float*)d_in[7];
  const float* W2 = (const float*)d_in[8];
  const float* b2 = (const float*)d_in[9];
  float* out = (float*)d_out;
  const int nspans = in_sizes[1];       // 131072
  const int nblk = nspans / SPB;        // 2048

  float* partials = (float*)d_ws;                                    // 32 KiB
  unsigned short* W1b = (unsigned short*)((char*)d_ws + (1 << 18));  // 1 MiB blocked
  unsigned char* Wq = (unsigned char*)((char*)d_ws + (2 << 20));     // 16.8 MiB
  int* ghist = (int*)((char*)d_ws + (19 << 20));                     // 32 ints
  int* gslot = ghist + 32;                                           // 32 ints
  int* sidx  = (int*)((char*)d_ws + (20 << 20));                     // 512 KiB

  hipMemsetAsync(ghist, 0, 64 * sizeof(int), stream);
  w1_blocked<<<256, 256, 0, stream>>>(W1, W1b);
  span_hist<<<(nspans + 1023) / 1024, 256, 0, stream>>>(bids, ghist, nspans);
  span_scatter<<<(nspans + 511) / 512, 256, 0, stream>>>(bids, ghist, gslot,
                                                         sidx, nspans);
  proj_gemm<<<dim3(256, 2), 512, 0, stream>>>(hidden, W1b, Wq);
  span_eval<<<nblk, 256, 0, stream>>>(Wq, sidx, bids, begins, ends, flags,
                                      weights, b1, W2, b2, partials);
  finalize<<<1, 256, 0, stream>>>(partials, nblk, out, nspans);
}